// Round 8
// baseline (6631.653 us; speedup 1.0000x reference)
//
#include <hip/hip_runtime.h>
#include <hip/hip_bf16.h>

typedef __attribute__((ext_vector_type(8))) short bf16x8;
typedef __attribute__((ext_vector_type(4))) float f32x4;

#define T_STEPS 256
#define BATCH   64
#define KDIM    1024
#define HDIM    1024
#define NGATE   3072   // 3*HDIM
#define LAYERS  3
#define SLOTE   (BATCH * HDIM)       // elements per h slot [64][1024]
#define RING_SLOTS (T_STEPS + 1)
#define WSZ     (192L * 32 * 64 * 8) // swizzled weight elems per layer

#define MFMA16(a, b, c) __builtin_amdgcn_mfma_f32_16x16x32_bf16(a, b, c, 0, 0, 0)

// ---------- helpers (byte-identical to R6/R7) ----------
__device__ __forceinline__ unsigned short f2b(float f) {
  union { float f; unsigned int u; } a; a.f = f;
  unsigned int u = a.u;
  unsigned int r = (u + 0x7FFFu + ((u >> 16) & 1u)) >> 16;  // RNE
  return (unsigned short)r;
}
__device__ __forceinline__ void gload16(const void* gptr, void* ldsptr) {
  __builtin_amdgcn_global_load_lds(
      (const __attribute__((address_space(1))) unsigned int*)gptr,
      (__attribute__((address_space(3))) unsigned int*)ldsptr,
      16, 0, 0);
}

// ---------- fp32 -> bf16 bulk convert (4 elems/thread) ----------
__global__ void f2b_kernel(const float* __restrict__ src,
                           unsigned short* __restrict__ dst, int n4) {
  int i = blockIdx.x * blockDim.x + threadIdx.x;
  if (i < n4) {
    float4 v = ((const float4*)src)[i];
    ushort4 o;
    o.x = f2b(v.x); o.y = f2b(v.y); o.z = f2b(v.z); o.w = f2b(v.w);
    ((ushort4*)dst)[i] = o;
  }
}

// ---------- swizzle a [3][3072][1024] fp32 matrix into MFMA B-frag layout ----------
// out: [l][ntile(192)][kc(32)][lane(64)][8 bf16]
__global__ void swizzle_w(const float* __restrict__ w,
                          unsigned short* __restrict__ out) {
  long gid = (long)blockIdx.x * 256 + threadIdx.x;   // < 3*192*32*64
  int lane = (int)(gid & 63);
  long rest = gid >> 6;
  int kc = (int)(rest & 31); rest >>= 5;
  int ntile = (int)(rest % 192); int l = (int)(rest / 192);
  int n  = ntile * 16 + (lane & 15);
  int k0 = kc * 32 + (lane >> 4) * 8;
  const float* src = w + (((long)l * NGATE + n) * KDIM + k0);
  unsigned short o[8];
#pragma unroll
  for (int j = 0; j < 8; j++) o[j] = f2b(src[j]);
  bf16x8 v = *(bf16x8*)o;
  *(bf16x8*)(out + gid * 8) = v;
}

// ---------- fused 3-layer GRU, PLAIN launch, 192 wgs x 256 thr ----------
// wg = (layer l = blockIdx.x>>6, colgroup g = blockIdx.x&63). Structure identical
// to R7 EXCEPT register diet: no bn[32] (Whh-n streamed from L2 like Wih gates),
// A-fragments chunked 8-at-a-time (ha[8]/xa[8]) instead of ha[32] upfront.
// R7's VGPR_Count=256 + (FETCH+226MB, WRITE+52MB) = scratch spills; this removes them.
__global__ __launch_bounds__(256, 1) void gru_fused(
    const unsigned short* __restrict__ xb,     // [T][64][1024] bf16 layer-0 input
    const unsigned short* __restrict__ wswhh,  // [3][WSZ] swizzled Whh
    const unsigned short* __restrict__ wswih,  // [3][WSZ] swizzled Wih
    const float* __restrict__ bih,             // [3][3072]
    const float* __restrict__ bhh,             // [3][3072]
    const float* __restrict__ h0,              // [3][64][1024]
    unsigned short* __restrict__ rings,        // [3][257][64][1024] bf16
    float* __restrict__ hout,                  // [3][64][1024] = d_out
    unsigned int* __restrict__ flags)          // [3][64], memset 0
{
  __shared__ alignas(16) unsigned short Bs[64 * 64 * 8];   // Whh r,z frags (64 KB)
  int l = blockIdx.x >> 6, g = blockIdx.x & 63;
  int tid = threadIdx.x, wave = tid >> 6, lane = tid & 63;
  int colc = g * 16 + (lane & 15);
  int rowb = wave * 16 + ((lane >> 4) << 2);

  const unsigned short* whh_l = wswhh + (size_t)l * WSZ;
  const unsigned short* wih_l = wswih + (size_t)l * WSZ;
  unsigned short* ring_l = rings + (size_t)l * RING_SLOTS * SLOTE;
  const unsigned short* prev_ring = rings + (size_t)(l - 1) * RING_SLOTS * SLOTE;
  unsigned int* fl = flags + l * 64;
  const unsigned int* fp = flags + (l > 0 ? (l - 1) : 0) * 64;

  // ---- stage Whh r,z into LDS ----
#pragma unroll
  for (int i = 0; i < 16; i++) {
    int p = wave * 16 + i;                     // 0..63 = gate*32+kc
    int gate = p >> 5, kc = p & 31;
    gload16(whh_l + ((((long)gate * 64 + g) * 32 + kc) * 64 + lane) * 8,
            &Bs[(size_t)p * 512 + (size_t)lane * 8]);
  }

  float bhr = bhh[l * NGATE + 0 * HDIM + colc];
  float bhz = bhh[l * NGATE + 1 * HDIM + colc];
  float bhn = bhh[l * NGATE + 2 * HDIM + colc];
  float bir = bih[l * NGATE + 0 * HDIM + colc];
  float biz = bih[l * NGATE + 1 * HDIM + colc];
  float bin_ = bih[l * NGATE + 2 * HDIM + colc];

  // ---- publish h(0)=h0 into own ring slot T (agent scope) ----
  float h[4];
  unsigned short* slotT = ring_l + (size_t)T_STEPS * SLOTE;
#pragma unroll
  for (int r = 0; r < 4; r++) {
    h[r] = h0[l * SLOTE + (rowb + r) * HDIM + colc];
    __hip_atomic_store(slotT + (rowb + r) * HDIM + colc, f2b(h[r]),
                       __ATOMIC_RELAXED, __HIP_MEMORY_SCOPE_AGENT);
  }
  __syncthreads();   // drains vmcnt: Bs staged + h0 at LLC
  if (tid == 0)
    __hip_atomic_store(&fl[g], 1u, __ATOMIC_RELAXED, __HIP_MEMORY_SCOPE_AGENT);

  // pre-loop wait: own h0 published everywhere; prev layer finished step 0
  while (__hip_atomic_load(&fl[lane], __ATOMIC_RELAXED,
                           __HIP_MEMORY_SCOPE_AGENT) < 1u) {}
  if (l > 0) {
    while (__hip_atomic_load(&fp[lane], __ATOMIC_RELAXED,
                             __HIP_MEMORY_SCOPE_AGENT) < 2u) {}
  }
  __syncthreads();

#pragma unroll 1
  for (int t = 0; t < T_STEPS; t++) {
    // ---- addresses: own h(t) at slot (T-t); x(t) = xb[t] or prev slot (T-1-t) ----
    const unsigned short* ha_b = ring_l + (size_t)(T_STEPS - t) * SLOTE
                                 + (size_t)(wave * 16 + (lane & 15)) * HDIM
                                 + (size_t)(lane >> 4) * 8;
    const unsigned short* xrow = (l == 0)
        ? xb + (size_t)t * SLOTE
        : prev_ring + (size_t)(T_STEPS - 1 - t) * SLOTE;
    const unsigned short* xa_b = xrow + (size_t)(wave * 16 + (lane & 15)) * HDIM
                                      + (size_t)(lane >> 4) * 8;

    // ---- 6 GEMV accumulators; K processed in 4 chunks of 8 kc ----
    f32x4 air = {}, aiz = {}, ain = {};
    f32x4 ahr = {}, ahz = {}, ahn = {};
#pragma unroll
    for (int kb = 0; kb < 4; kb++) {
      bf16x8 ha[8], xa[8];
#pragma unroll
      for (int j = 0; j < 8; j++) {
        ha[j] = *(const bf16x8*)(ha_b + (kb * 8 + j) * 32);
        xa[j] = *(const bf16x8*)(xa_b + (kb * 8 + j) * 32);
      }
#pragma unroll
      for (int j = 0; j < 8; j++) {
        int kc = kb * 8 + j;
        bf16x8 wir = *(const bf16x8*)(wih_l + ((((long)(0 * 64 + g)) * 32 + kc) * 64 + lane) * 8);
        bf16x8 wiz = *(const bf16x8*)(wih_l + ((((long)(1 * 64 + g)) * 32 + kc) * 64 + lane) * 8);
        bf16x8 win = *(const bf16x8*)(wih_l + ((((long)(2 * 64 + g)) * 32 + kc) * 64 + lane) * 8);
        bf16x8 whn = *(const bf16x8*)(whh_l + ((((long)(2 * 64 + g)) * 32 + kc) * 64 + lane) * 8);
        bf16x8 whr = *(const bf16x8*)&Bs[(size_t)(0 * 32 + kc) * 512 + (size_t)lane * 8];
        bf16x8 whz = *(const bf16x8*)&Bs[(size_t)(1 * 32 + kc) * 512 + (size_t)lane * 8];
        air = MFMA16(xa[j], wir, air);
        aiz = MFMA16(xa[j], wiz, aiz);
        ain = MFMA16(xa[j], win, ain);
        ahr = MFMA16(ha[j], whr, ahr);
        ahz = MFMA16(ha[j], whz, ahz);
        ahn = MFMA16(ha[j], whn, ahn);
      }
    }

    // ---- gates + state update (C/D: col=lane&15, row=(lane>>4)*4+reg) ----
    unsigned short* hn = ring_l + (size_t)(T_STEPS - 1 - t) * SLOTE;  // h(t+1)
#pragma unroll
    for (int r = 0; r < 4; r++) {
      float xr = air[r] + bir + ahr[r] + bhr;
      float xz = aiz[r] + biz + ahz[r] + bhz;
      float rr = 1.0f / (1.0f + __expf(-xr));
      float zz = 1.0f / (1.0f + __expf(-xz));
      float xn = (ain[r] + bin_) + rr * (ahn[r] + bhn);
      float e2 = __expf(-2.0f * xn);
      float nn = (1.0f - e2) / (1.0f + e2);    // tanh
      float hv = (1.0f - zz) * nn + zz * h[r];
      h[r] = hv;
      __hip_atomic_store(hn + (rowb + r) * HDIM + colc, f2b(hv),
                         __ATOMIC_RELAXED, __HIP_MEMORY_SCOPE_AGENT);
      if (t == T_STEPS - 1) hout[l * SLOTE + (rowb + r) * HDIM + colc] = hv;
    }

    // ---- barrier (R6 idiom): drain, flag-store arrive, flag-vector wait ----
    __syncthreads();                           // all waves' h(t+1) stores at LLC
    if (tid == 0)
      __hip_atomic_store(&fl[g], (unsigned)(t + 2),
                         __ATOMIC_RELAXED, __HIP_MEMORY_SCOPE_AGENT);
    if (t + 1 < T_STEPS) {
      while (__hip_atomic_load(&fl[lane], __ATOMIC_RELAXED,
                               __HIP_MEMORY_SCOPE_AGENT) < (unsigned)(t + 2)) {}
      if (l > 0) {
        while (__hip_atomic_load(&fp[lane], __ATOMIC_RELAXED,
                                 __HIP_MEMORY_SCOPE_AGENT) < (unsigned)(t + 3)) {}
      }
    }
    __syncthreads();
  }
}

// ---------- host ----------
extern "C" void kernel_launch(void* const* d_in, const int* in_sizes, int n_in,
                              void* d_out, int out_size, void* d_ws, size_t ws_size,
                              hipStream_t stream) {
  const float* x   = (const float*)d_in[0];
  const float* h0  = (const float*)d_in[1];
  const float* wih = (const float*)d_in[2];
  const float* whh = (const float*)d_in[3];
  const float* bih = (const float*)d_in[4];
  const float* bhh = (const float*)d_in[5];
  float* out = (float*)d_out;

  char* p = (char*)d_ws;
  unsigned short* xb    = (unsigned short*)p; p += (size_t)T_STEPS * SLOTE * 2;             // 33.6 MB
  unsigned short* wswhh = (unsigned short*)p; p += (size_t)LAYERS * WSZ * 2;                // 18.9 MB
  unsigned short* wswih = (unsigned short*)p; p += (size_t)LAYERS * WSZ * 2;                // 18.9 MB
  unsigned short* rings = (unsigned short*)p; p += (size_t)LAYERS * RING_SLOTS * SLOTE * 2; // 101 MB
  unsigned int*   flags = (unsigned int*)p;   p += 4096;
  // total ~172.5 MB (R4/R6 proved ws_size >= ~239 MB)

  hipMemsetAsync(flags, 0, 4096, stream);
  f2b_kernel<<<16384, 256, 0, stream>>>(x, xb, (T_STEPS * SLOTE) / 4);
  swizzle_w<<<4608, 256, 0, stream>>>(whh, wswhh);
  swizzle_w<<<4608, 256, 0, stream>>>(wih, wswih);

  gru_fused<<<LAYERS * 64, 256, 0, stream>>>(
      xb, wswhh, wswih, bih, bhh, h0, rings, out, flags);
}